// Round 15
// baseline (166.117 us; speedup 1.0000x reference)
//
#include <hip/hip_runtime.h>
#include <hip/hip_bf16.h>

typedef __bf16 bf16x8 __attribute__((ext_vector_type(8)));
typedef float f32x4 __attribute__((ext_vector_type(4)));
typedef float f32x16 __attribute__((ext_vector_type(16)));

#define SEQ   2048
#define NHEAD 12
#define NBH   24
#define QSCALE 0.18033688011112042f   // head_dim^-0.5 * log2(e)

// async global->LDS 16B copy; lds dest must be wave-uniform base + lane*16
#define CP16(g, l) __builtin_amdgcn_global_load_lds( \
    (const __attribute__((address_space(1))) unsigned int*)(g), \
    (__attribute__((address_space(3))) unsigned int*)(l), 16, 0, 0)

__device__ __forceinline__ unsigned short f2bf(float f) {
  unsigned int u = __builtin_bit_cast(unsigned int, f);
  u += 0x7FFFu + ((u >> 16) & 1u);
  return (unsigned short)(u >> 16);
}
__device__ __forceinline__ float bfu2f(unsigned int lo16_as_hi) {
  return __builtin_bit_cast(float, lo16_as_hi);
}
// truncating pack of two f32 -> bf16x2 in one v_perm_b32 (P in [0,1]; dominant weight is
// exactly 1.0 under running-max so top terms carry zero pack error — PROVEN at 1.95e-3)
__device__ __forceinline__ unsigned int packbf2_trunc(float lo, float hi) {
  return __builtin_amdgcn_perm(__builtin_bit_cast(unsigned int, hi),
                               __builtin_bit_cast(unsigned int, lo), 0x07060302u);
}

// ---------------------------------------------------------------- fused cvt fp32->bf16
#define NX4  786432
#define NW14 442368
__global__ __launch_bounds__(256) void cvt3_kernel(const float4* __restrict__ x,
                                                   const float4* __restrict__ w1,
                                                   const float4* __restrict__ w2,
                                                   ushort4* __restrict__ xo,
                                                   ushort4* __restrict__ w1o,
                                                   ushort4* __restrict__ w2o) {
  int i = blockIdx.x * 256 + threadIdx.x;
  const float4* s;
  ushort4* d;
  int j = i;
  if (i < NX4)               { s = x;  d = xo; }
  else if (i < NX4 + NW14)   { s = w1; d = w1o; j = i - NX4; }
  else                       { s = w2; d = w2o; j = i - (NX4 + NW14); }
  float4 v = s[j];
  ushort4 r;
  r.x = f2bf(v.x); r.y = f2bf(v.y); r.z = f2bf(v.z); r.w = f2bf(v.w);
  d[j] = r;
}

// ---------------------------------------------------------------- GEMM  C = X @ W^T (+bias)
// Round-15: gemm1 gets the R14-proven mechanism — MORE WAVES PER STAGED TILE.
// 128x128 tile, 512 threads = 8 waves (2Mx4N, per-wave 64x32, acc 32 VGPR — no R12 spill):
// staged-bytes-per-FLOP 26 -> 15.6 B/KFLOP, waves served per barrier 4 -> 8. Grid (18,32)
// = 576 blocks (~2.25/CU, 32 KB LDS -> up to 5 resident). Template unchanged (NTH-generic,
// single-buffered); only the launch config moves. gemm2 stays R13 (64x96 @ 256t).
template <int BM, int BN, int NTH, int MODE>
__global__ __launch_bounds__(NTH) void gemm_kernel(const unsigned short* __restrict__ X,
                                                   const unsigned short* __restrict__ W,
                                                   const float* __restrict__ bias,
                                                   unsigned short* __restrict__ Qb,
                                                   unsigned short* __restrict__ Kb,
                                                   unsigned short* __restrict__ Vtb,
                                                   float* __restrict__ Out) {
  constexpr int K = 768, BK = 64;
  constexpr int WAVES_N = (NTH / 64) / 2;
  constexpr int WM = BM / 2, WN = BN / WAVES_N;
  constexpr int MT = WM / 16, NT = WN / 16;
  __shared__ __align__(16) unsigned short Xs[BM * BK];
  __shared__ __align__(16) unsigned short Ws[BN * BK];

  const int tid = threadIdx.x;
  const int w = tid >> 6, lane = tid & 63, quad = lane >> 4, m16 = lane & 15;
  const int wm = w & 1, wn = w >> 1;
  const int row0 = blockIdx.y * BM, col0 = blockIdx.x * BN;

  f32x4 acc[MT][NT];
#pragma unroll
  for (int mt = 0; mt < MT; ++mt)
#pragma unroll
    for (int nt = 0; nt < NT; ++nt) acc[mt][nt] = (f32x4){0.f, 0.f, 0.f, 0.f};

  for (int k0 = 0; k0 < K; k0 += BK) {
    __syncthreads();
#pragma unroll
    for (int j = 0; j < BM * 8 / NTH; ++j) {
      int e = tid + NTH * j, r = e >> 3, c8 = e & 7;
      CP16(X + (size_t)(row0 + r) * 768 + k0 + ((c8 ^ (r & 7)) << 3), Xs + e * 8);
    }
#pragma unroll
    for (int j = 0; j < BN * 8 / NTH; ++j) {
      int e = tid + NTH * j, r = e >> 3, c8 = e & 7;
      CP16(W + (size_t)(col0 + r) * 768 + k0 + ((c8 ^ (r & 7)) << 3), Ws + e * 8);
    }
    __syncthreads();
#pragma unroll
    for (int ks = 0; ks < 2; ++ks) {
      const int sw = ((quad + 4 * ks) ^ (m16 & 7)) << 3;
      bf16x8 a[MT], b[NT];
#pragma unroll
      for (int mt = 0; mt < MT; ++mt)
        a[mt] = *(const bf16x8*)(Xs + (wm * WM + mt * 16 + m16) * BK + sw);
#pragma unroll
      for (int nt = 0; nt < NT; ++nt)
        b[nt] = *(const bf16x8*)(Ws + (wn * WN + nt * 16 + m16) * BK + sw);
#pragma unroll
      for (int mt = 0; mt < MT; ++mt)
#pragma unroll
        for (int nt = 0; nt < NT; ++nt)
          acc[mt][nt] = __builtin_amdgcn_mfma_f32_16x16x32_bf16(a[mt], b[nt], acc[mt][nt], 0, 0, 0);
    }
  }

#pragma unroll
  for (int mt = 0; mt < MT; ++mt) {
#pragma unroll
    for (int nt = 0; nt < NT; ++nt) {
      const int m0 = row0 + wm * WM + mt * 16 + quad * 4;
      const int c = col0 + wn * WN + nt * 16 + m16;
      const float bia = bias[c];
      f32x4 v = acc[mt][nt];
      if constexpr (MODE == 0) {
        const int bidx = m0 >> 11, ns = m0 & 2047;
        if (c < 1536) {   // Q or K: [bh][n][d]
          unsigned short* dst;
          float sc;
          int cc;
          if (c < 768) { cc = c; dst = Qb; sc = QSCALE; }
          else         { cc = c - 768; dst = Kb; sc = 1.0f; }
          const int h = cc >> 6, d = cc & 63;
          unsigned short* p = dst + ((size_t)(bidx * NHEAD + h) * SEQ + ns) * 64 + d;
          p[0]   = f2bf((v[0] + bia) * sc);
          p[64]  = f2bf((v[1] + bia) * sc);
          p[128] = f2bf((v[2] + bia) * sc);
          p[192] = f2bf((v[3] + bia) * sc);
        } else {          // V transposed [bh][d][n], sigma-permuted keys (bits2<->3 of n&15)
          const int cc = c - 1536, h = cc >> 6, d = cc & 63;
          const int ns2 = (ns & ~12) | ((ns & 4) << 1) | ((ns & 8) >> 1);
          ushort4 pk;
          pk.x = f2bf(v[0] + bia); pk.y = f2bf(v[1] + bia);
          pk.z = f2bf(v[2] + bia); pk.w = f2bf(v[3] + bia);
          *(ushort4*)(Vtb + ((size_t)(bidx * NHEAD + h) * 64 + d) * SEQ + ns2) = pk;
        }
      } else {
        float* o = Out + (size_t)m0 * 768 + c;
        o[0]       = v[0] + bia;
        o[768]     = v[1] + bia;
        o[2 * 768] = v[2] + bia;
        o[3 * 768] = v[3] + bia;
      }
    }
  }
}

// ---------------------------------------------------------------- flash attention
// R14 kernel (measured 51.2 µs — the 4-wave-block win). 768 blocks = 24 bh x 16
// q-tiles(128) x 2 key-halves; 256 threads = 4 waves x 32 q. Each staged 16 KB K/V tile +
// barrier serves 2x the q-rows of the R0 structure. Per-wave inner loop = R0 verbatim.
// Key-split epilogue + combine proven (absmax 1.953e-3).
__global__ __launch_bounds__(256) void attn_kernel(const unsigned short* __restrict__ Qb,
                                                   const unsigned short* __restrict__ Kb,
                                                   const unsigned short* __restrict__ Vtb,
                                                   unsigned short* __restrict__ O0,
                                                   unsigned short* __restrict__ O1,
                                                   float2* __restrict__ ml) {
  __shared__ __align__(16) unsigned short Ks[2][64 * 64];
  __shared__ __align__(16) unsigned short Vts[2][64 * 64];

  const int tid = threadIdx.x;
  const int w = tid >> 6, lane = tid & 63, hi = lane >> 5, l32 = lane & 31;
  const int bh = blockIdx.x % NBH;          // same bh -> same XCD (24%8==0, 768%24==0)
  const int rest = blockIdx.x / NBH;        // [0,32)
  const int qt = rest & 15, half = rest >> 4;
  const int bb = bh / NHEAD, h = bh % NHEAD;
  const int q0 = qt * 128 + w * 32;         // wave w owns q rows [q0, q0+32)

  const unsigned short* Qp = Qb + (size_t)bh * SEQ * 64;
  const unsigned short* Kp = Kb + (size_t)bh * SEQ * 64 + (size_t)half * 16 * 4096;
  const unsigned short* Vp = Vtb + (size_t)bh * 64 * SEQ + half * 1024;

  // Q B-frags: lane holds Q[q0+l32][dc*16 + hi*8 + j]
  bf16x8 qf[4];
#pragma unroll
  for (int dc = 0; dc < 4; ++dc)
    qf[dc] = *(const bf16x8*)(Qp + (size_t)(q0 + l32) * 64 + dc * 16 + hi * 8);

  // prologue: stage tile 0 (of this half) into buf 0 — 256 threads, j<2 covers 512 chunks
#pragma unroll
  for (int j = 0; j < 2; ++j) {
    int e = tid + 256 * j, r = e >> 3, c8 = e & 7;
    CP16(Kp + (size_t)r * 64 + ((c8 ^ (r & 7)) << 3), &Ks[0][e * 8]);
    CP16(Vp + (size_t)r * SEQ + ((c8 ^ (r & 7)) << 3), &Vts[0][e * 8]);
  }

  f32x16 o[2] = {};
  float m_i = -3.0e38f, l_i = 0.f;

  for (int kt = 0; kt < 16; ++kt) {
    const int cur = kt & 1;
    __syncthreads();   // drains vmcnt -> buf[cur] ready; all waves done reading buf[1-cur]

    const unsigned short* Kc = Ks[cur];
    const unsigned short* Vc = Vts[cur];
    // frag loads first (ds_read), then prefetch issue, then MFMA/VALU
    bf16x8 kf[2][4], vf[2][4];
#pragma unroll
    for (int t32 = 0; t32 < 2; ++t32)
#pragma unroll
      for (int dc = 0; dc < 4; ++dc)
        kf[t32][dc] = *(const bf16x8*)(Kc + (t32 * 32 + l32) * 64 + ((((dc << 1) | hi) ^ (l32 & 7)) << 3));
#pragma unroll
    for (int dt = 0; dt < 2; ++dt)
#pragma unroll
      for (int cc = 0; cc < 4; ++cc)
        vf[dt][cc] = *(const bf16x8*)(Vc + (dt * 32 + l32) * 64 + ((((cc << 1) | hi) ^ (l32 & 7)) << 3));

    if (kt < 15) {     // async prefetch next tile into buf[1-cur]
      const int kn = kt + 1, nb = 1 - cur;
#pragma unroll
      for (int j = 0; j < 2; ++j) {
        int e = tid + 256 * j, r = e >> 3, c8 = e & 7;
        CP16(Kp + (size_t)(kn * 64 + r) * 64 + ((c8 ^ (r & 7)) << 3), &Ks[nb][e * 8]);
        CP16(Vp + (size_t)r * SEQ + kn * 64 + ((c8 ^ (r & 7)) << 3), &Vts[nb][e * 8]);
      }
    }

    // S^T: st[t32] holds S^T[key = t32*32 + (r&3)+8*(r>>2)+4*hi][q = l32]
    f32x16 st[2];
#pragma unroll
    for (int t32 = 0; t32 < 2; ++t32) {
      f32x16 s = {};
#pragma unroll
      for (int dc = 0; dc < 4; ++dc)
        s = __builtin_amdgcn_mfma_f32_32x32x16_bf16(kf[t32][dc], qf[dc], s, 0, 0, 0);
      st[t32] = s;
    }

    // online softmax: lane holds 32 scores; partner (^32) has the other 32
    float tmax = st[0][0];
#pragma unroll
    for (int t32 = 0; t32 < 2; ++t32)
#pragma unroll
      for (int e = 0; e < 16; ++e) tmax = fmaxf(tmax, st[t32][e]);
    tmax = fmaxf(tmax, __shfl_xor(tmax, 32));
    const float mnew = fmaxf(m_i, tmax);
    const float alpha = __builtin_amdgcn_exp2f(m_i - mnew);
    float ssum = 0.f;
    unsigned int pf[2][8];
#pragma unroll
    for (int t32 = 0; t32 < 2; ++t32) {
      float pv[16];
#pragma unroll
      for (int e = 0; e < 16; ++e) { pv[e] = __builtin_amdgcn_exp2f(st[t32][e] - mnew); ssum += pv[e]; }
#pragma unroll
      for (int e2 = 0; e2 < 8; ++e2)
        pf[t32][e2] = packbf2_trunc(pv[2 * e2], pv[2 * e2 + 1]);
    }
    ssum += __shfl_xor(ssum, 32);
    l_i = l_i * alpha + ssum;
    m_i = mnew;
    o[0] *= alpha;
    o[1] *= alpha;

    // O^T += Vt . P^T
#pragma unroll
    for (int t32 = 0; t32 < 2; ++t32) {
#pragma unroll
      for (int hh = 0; hh < 2; ++hh) {
        bf16x8 pfrag = __builtin_bit_cast(bf16x8,
            make_uint4(pf[t32][hh * 4], pf[t32][hh * 4 + 1], pf[t32][hh * 4 + 2], pf[t32][hh * 4 + 3]));
        const int cc = 2 * t32 + hh;
#pragma unroll
        for (int dt = 0; dt < 2; ++dt)
          o[dt] = __builtin_amdgcn_mfma_f32_32x32x16_bf16(vf[dt][cc], pfrag, o[dt], 0, 0, 0);
      }
    }
  }

  // epilogue: write UNNORMALIZED O partial (bf16 RNE) + (m,l); combine normalizes.
  // lane's q = q0 + l32; o element d = dt*32 + 8*(r>>2) + 4*hi + (r&3)
  unsigned short* base = (half ? O1 : O0) + ((size_t)bb * SEQ + q0 + l32) * 768 + h * 64;
#pragma unroll
  for (int dt = 0; dt < 2; ++dt) {
#pragma unroll
    for (int run = 0; run < 4; ++run) {
      ushort4 pk;
      pk.x = f2bf(o[dt][run * 4 + 0]);
      pk.y = f2bf(o[dt][run * 4 + 1]);
      pk.z = f2bf(o[dt][run * 4 + 2]);
      pk.w = f2bf(o[dt][run * 4 + 3]);
      *(ushort4*)(base + dt * 32 + run * 8 + hi * 4) = pk;
    }
  }
  if (hi == 0)
    ml[(size_t)half * (NBH * SEQ) + bh * SEQ + q0 + l32] = make_float2(m_i, l_i);
}

// ---------------------------------------------------------------- combine partial halves
// O = (a0*O0 + a1*O1) / (a0*l0 + a1*l1), a_i = exp2(m_i - max(m0,m1)). In-place into O0.
// (proven correct in rounds 4/10/14, absmax 1.953e-3)
__global__ __launch_bounds__(256) void combine_kernel(unsigned short* __restrict__ O0,
                                                      const unsigned short* __restrict__ O1,
                                                      const float2* __restrict__ ml) {
  const int gid = blockIdx.x * 256 + threadIdx.x;   // [0, 196608)
  const int t = gid / 48, ci = gid - t * 48;        // token, 16-ch chunk
  const int ch0 = ci * 16, h = ch0 >> 6;
  const int mlrow = ((t >> 11) * NHEAD + h) * SEQ + (t & 2047);
  const float2 ml0 = ml[mlrow], ml1 = ml[NBH * SEQ + mlrow];
  const float m = fmaxf(ml0.x, ml1.x);
  const float a0 = __builtin_amdgcn_exp2f(ml0.x - m);
  const float a1 = __builtin_amdgcn_exp2f(ml1.x - m);
  const float rl = __builtin_amdgcn_rcpf(a0 * ml0.y + a1 * ml1.y);
  const float s0 = a0 * rl, s1 = a1 * rl;
  unsigned short* p0 = O0 + (size_t)t * 768 + ch0;
  const unsigned short* p1 = O1 + (size_t)t * 768 + ch0;
  uint4 x[2], y[2];
  x[0] = *(const uint4*)p0;       x[1] = *(const uint4*)(p0 + 8);
  y[0] = *(const uint4*)p1;       y[1] = *(const uint4*)(p1 + 8);
#pragma unroll
  for (int q = 0; q < 2; ++q) {
    unsigned int* xu = (unsigned int*)&x[q];
    const unsigned int* yu = (const unsigned int*)&y[q];
#pragma unroll
    for (int e = 0; e < 4; ++e) {
      const unsigned int u0 = xu[e], u1 = yu[e];
      const float lo = bfu2f(u0 << 16) * s0 + bfu2f(u1 << 16) * s1;
      const float hi = bfu2f(u0 & 0xFFFF0000u) * s0 + bfu2f(u1 & 0xFFFF0000u) * s1;
      xu[e] = ((unsigned int)f2bf(hi) << 16) | f2bf(lo);
    }
  }
  *(uint4*)p0 = x[0];
  *(uint4*)(p0 + 8) = x[1];
}

// ---------------------------------------------------------------- launch
extern "C" void kernel_launch(void* const* d_in, const int* in_sizes, int n_in,
                              void* d_out, int out_size, void* d_ws, size_t ws_size,
                              hipStream_t stream) {
  const float* x      = (const float*)d_in[0];
  const float* qkv_w  = (const float*)d_in[1];
  const float* qkv_b  = (const float*)d_in[2];
  const float* proj_w = (const float*)d_in[3];
  const float* proj_b = (const float*)d_in[4];
  float* out = (float*)d_out;

  unsigned short* xb  = (unsigned short*)d_ws;     // dead after gemm1 -> O1 partial
  unsigned short* wqb = xb + 3145728;              // dead after gemm1 -> ml partials
  unsigned short* wpb = wqb + 1769472;
  unsigned short* Qb  = wpb + 589824;
  unsigned short* Kb  = Qb + 3145728;
  unsigned short* Vtb = Kb + 3145728;
  unsigned short* Ab  = Vtb + 3145728;             // O0 partial, combined in-place

  cvt3_kernel<<<5376, 256, 0, stream>>>((const float4*)x, (const float4*)qkv_w, (const float4*)proj_w,
                                        (ushort4*)xb, (ushort4*)wqb, (ushort4*)wpb);
  // gemm1: 128x128 @ 512 threads (8 waves/tile — R14 mechanism), grid (18,32) = 576 blocks
  gemm_kernel<128, 128, 512, 0><<<dim3(18, 32), 512, 0, stream>>>(xb, wqb, qkv_b, Qb, Kb, Vtb, nullptr);
  // attn: 4-wave blocks, 2-way key split (R14, measured 51.2 µs)
  attn_kernel<<<768, 256, 0, stream>>>(Qb, Kb, Vtb, Ab, xb, (float2*)wqb);
  combine_kernel<<<768, 256, 0, stream>>>(Ab, xb, (const float2*)wqb);
  gemm_kernel<64, 96, 256, 1><<<dim3(8, 64), 256, 0, stream>>>(Ab, wpb, proj_b, nullptr, nullptr, nullptr, out);
}

// Round 16
// 164.096 us; speedup vs baseline: 1.0123x; 1.0123x over previous
//
#include <hip/hip_runtime.h>
#include <hip/hip_bf16.h>

typedef __bf16 bf16x8 __attribute__((ext_vector_type(8)));
typedef float f32x4 __attribute__((ext_vector_type(4)));
typedef float f32x16 __attribute__((ext_vector_type(16)));

#define SEQ   2048
#define NHEAD 12
#define NBH   24
#define QSCALE 0.18033688011112042f   // head_dim^-0.5 * log2(e)

// async global->LDS 16B copy; lds dest must be wave-uniform base + lane*16
#define CP16(g, l) __builtin_amdgcn_global_load_lds( \
    (const __attribute__((address_space(1))) unsigned int*)(g), \
    (__attribute__((address_space(3))) unsigned int*)(l), 16, 0, 0)

__device__ __forceinline__ unsigned short f2bf(float f) {
  unsigned int u = __builtin_bit_cast(unsigned int, f);
  u += 0x7FFFu + ((u >> 16) & 1u);
  return (unsigned short)(u >> 16);
}
__device__ __forceinline__ float bfu2f(unsigned int lo16_as_hi) {
  return __builtin_bit_cast(float, lo16_as_hi);
}
// truncating pack of two f32 -> bf16x2 in one v_perm_b32 (P in [0,1]; dominant weight is
// exactly 1.0 under running-max so top terms carry zero pack error — PROVEN at 1.95e-3)
__device__ __forceinline__ unsigned int packbf2_trunc(float lo, float hi) {
  return __builtin_amdgcn_perm(__builtin_bit_cast(unsigned int, hi),
                               __builtin_bit_cast(unsigned int, lo), 0x07060302u);
}

// ---------------------------------------------------------------- fused cvt fp32->bf16
#define NX4  786432
#define NW14 442368
__global__ __launch_bounds__(256) void cvt3_kernel(const float4* __restrict__ x,
                                                   const float4* __restrict__ w1,
                                                   const float4* __restrict__ w2,
                                                   ushort4* __restrict__ xo,
                                                   ushort4* __restrict__ w1o,
                                                   ushort4* __restrict__ w2o) {
  int i = blockIdx.x * 256 + threadIdx.x;
  const float4* s;
  ushort4* d;
  int j = i;
  if (i < NX4)               { s = x;  d = xo; }
  else if (i < NX4 + NW14)   { s = w1; d = w1o; j = i - NX4; }
  else                       { s = w2; d = w2o; j = i - (NX4 + NW14); }
  float4 v = s[j];
  ushort4 r;
  r.x = f2bf(v.x); r.y = f2bf(v.y); r.z = f2bf(v.z); r.w = f2bf(v.w);
  d[j] = r;
}

// ---------------------------------------------------------------- GEMM  C = X @ W^T (+bias)
// Round-16: gemm1 retries the 8-waves-per-staged-tile lever with the R15 tail flaw fixed.
// 64x192 @ 512 threads (2Mx4N waves, per-wave 32x48, acc 24 VGPR — no spill risk):
// grid (12,64) = 768 blocks = EXACTLY 3 blocks/CU (R15's 576 = 2.25/CU tail was the
// confound). Each barrier event serves 8 waves; total staged volume 377 -> 301 MB.
// LDS 32 KB -> 3 blocks co-resident, 24 waves/CU supply (= R13). gemm2 stays R13 config.
template <int BM, int BN, int NTH, int MODE>
__global__ __launch_bounds__(NTH) void gemm_kernel(const unsigned short* __restrict__ X,
                                                   const unsigned short* __restrict__ W,
                                                   const float* __restrict__ bias,
                                                   unsigned short* __restrict__ Qb,
                                                   unsigned short* __restrict__ Kb,
                                                   unsigned short* __restrict__ Vtb,
                                                   float* __restrict__ Out) {
  constexpr int K = 768, BK = 64;
  constexpr int WAVES_N = (NTH / 64) / 2;
  constexpr int WM = BM / 2, WN = BN / WAVES_N;
  constexpr int MT = WM / 16, NT = WN / 16;
  __shared__ __align__(16) unsigned short Xs[BM * BK];
  __shared__ __align__(16) unsigned short Ws[BN * BK];

  const int tid = threadIdx.x;
  const int w = tid >> 6, lane = tid & 63, quad = lane >> 4, m16 = lane & 15;
  const int wm = w & 1, wn = w >> 1;
  const int row0 = blockIdx.y * BM, col0 = blockIdx.x * BN;

  f32x4 acc[MT][NT];
#pragma unroll
  for (int mt = 0; mt < MT; ++mt)
#pragma unroll
    for (int nt = 0; nt < NT; ++nt) acc[mt][nt] = (f32x4){0.f, 0.f, 0.f, 0.f};

  for (int k0 = 0; k0 < K; k0 += BK) {
    __syncthreads();
#pragma unroll
    for (int j = 0; j < BM * 8 / NTH; ++j) {
      int e = tid + NTH * j, r = e >> 3, c8 = e & 7;
      CP16(X + (size_t)(row0 + r) * 768 + k0 + ((c8 ^ (r & 7)) << 3), Xs + e * 8);
    }
#pragma unroll
    for (int j = 0; j < BN * 8 / NTH; ++j) {
      int e = tid + NTH * j, r = e >> 3, c8 = e & 7;
      CP16(W + (size_t)(col0 + r) * 768 + k0 + ((c8 ^ (r & 7)) << 3), Ws + e * 8);
    }
    __syncthreads();
#pragma unroll
    for (int ks = 0; ks < 2; ++ks) {
      const int sw = ((quad + 4 * ks) ^ (m16 & 7)) << 3;
      bf16x8 a[MT], b[NT];
#pragma unroll
      for (int mt = 0; mt < MT; ++mt)
        a[mt] = *(const bf16x8*)(Xs + (wm * WM + mt * 16 + m16) * BK + sw);
#pragma unroll
      for (int nt = 0; nt < NT; ++nt)
        b[nt] = *(const bf16x8*)(Ws + (wn * WN + nt * 16 + m16) * BK + sw);
#pragma unroll
      for (int mt = 0; mt < MT; ++mt)
#pragma unroll
        for (int nt = 0; nt < NT; ++nt)
          acc[mt][nt] = __builtin_amdgcn_mfma_f32_16x16x32_bf16(a[mt], b[nt], acc[mt][nt], 0, 0, 0);
    }
  }

#pragma unroll
  for (int mt = 0; mt < MT; ++mt) {
#pragma unroll
    for (int nt = 0; nt < NT; ++nt) {
      const int m0 = row0 + wm * WM + mt * 16 + quad * 4;
      const int c = col0 + wn * WN + nt * 16 + m16;
      const float bia = bias[c];
      f32x4 v = acc[mt][nt];
      if constexpr (MODE == 0) {
        const int bidx = m0 >> 11, ns = m0 & 2047;
        if (c < 1536) {   // Q or K: [bh][n][d]
          unsigned short* dst;
          float sc;
          int cc;
          if (c < 768) { cc = c; dst = Qb; sc = QSCALE; }
          else         { cc = c - 768; dst = Kb; sc = 1.0f; }
          const int h = cc >> 6, d = cc & 63;
          unsigned short* p = dst + ((size_t)(bidx * NHEAD + h) * SEQ + ns) * 64 + d;
          p[0]   = f2bf((v[0] + bia) * sc);
          p[64]  = f2bf((v[1] + bia) * sc);
          p[128] = f2bf((v[2] + bia) * sc);
          p[192] = f2bf((v[3] + bia) * sc);
        } else {          // V transposed [bh][d][n], sigma-permuted keys (bits2<->3 of n&15)
          const int cc = c - 1536, h = cc >> 6, d = cc & 63;
          const int ns2 = (ns & ~12) | ((ns & 4) << 1) | ((ns & 8) >> 1);
          ushort4 pk;
          pk.x = f2bf(v[0] + bia); pk.y = f2bf(v[1] + bia);
          pk.z = f2bf(v[2] + bia); pk.w = f2bf(v[3] + bia);
          *(ushort4*)(Vtb + ((size_t)(bidx * NHEAD + h) * 64 + d) * SEQ + ns2) = pk;
        }
      } else {
        float* o = Out + (size_t)m0 * 768 + c;
        o[0]       = v[0] + bia;
        o[768]     = v[1] + bia;
        o[2 * 768] = v[2] + bia;
        o[3 * 768] = v[3] + bia;
      }
    }
  }
}

// ---------------------------------------------------------------- flash attention
// R14 kernel (measured 50.7-51.4 µs — the 4-wave-block win). 768 blocks = 24 bh x 16
// q-tiles(128) x 2 key-halves; 256 threads = 4 waves x 32 q. Each staged 16 KB K/V tile +
// barrier serves 2x the q-rows of the R0 structure. Per-wave inner loop = R0 verbatim.
// Key-split epilogue + combine proven (absmax 1.953e-3).
__global__ __launch_bounds__(256) void attn_kernel(const unsigned short* __restrict__ Qb,
                                                   const unsigned short* __restrict__ Kb,
                                                   const unsigned short* __restrict__ Vtb,
                                                   unsigned short* __restrict__ O0,
                                                   unsigned short* __restrict__ O1,
                                                   float2* __restrict__ ml) {
  __shared__ __align__(16) unsigned short Ks[2][64 * 64];
  __shared__ __align__(16) unsigned short Vts[2][64 * 64];

  const int tid = threadIdx.x;
  const int w = tid >> 6, lane = tid & 63, hi = lane >> 5, l32 = lane & 31;
  const int bh = blockIdx.x % NBH;          // same bh -> same XCD (24%8==0, 768%24==0)
  const int rest = blockIdx.x / NBH;        // [0,32)
  const int qt = rest & 15, half = rest >> 4;
  const int bb = bh / NHEAD, h = bh % NHEAD;
  const int q0 = qt * 128 + w * 32;         // wave w owns q rows [q0, q0+32)

  const unsigned short* Qp = Qb + (size_t)bh * SEQ * 64;
  const unsigned short* Kp = Kb + (size_t)bh * SEQ * 64 + (size_t)half * 16 * 4096;
  const unsigned short* Vp = Vtb + (size_t)bh * 64 * SEQ + half * 1024;

  // Q B-frags: lane holds Q[q0+l32][dc*16 + hi*8 + j]
  bf16x8 qf[4];
#pragma unroll
  for (int dc = 0; dc < 4; ++dc)
    qf[dc] = *(const bf16x8*)(Qp + (size_t)(q0 + l32) * 64 + dc * 16 + hi * 8);

  // prologue: stage tile 0 (of this half) into buf 0 — 256 threads, j<2 covers 512 chunks
#pragma unroll
  for (int j = 0; j < 2; ++j) {
    int e = tid + 256 * j, r = e >> 3, c8 = e & 7;
    CP16(Kp + (size_t)r * 64 + ((c8 ^ (r & 7)) << 3), &Ks[0][e * 8]);
    CP16(Vp + (size_t)r * SEQ + ((c8 ^ (r & 7)) << 3), &Vts[0][e * 8]);
  }

  f32x16 o[2] = {};
  float m_i = -3.0e38f, l_i = 0.f;

  for (int kt = 0; kt < 16; ++kt) {
    const int cur = kt & 1;
    __syncthreads();   // drains vmcnt -> buf[cur] ready; all waves done reading buf[1-cur]

    const unsigned short* Kc = Ks[cur];
    const unsigned short* Vc = Vts[cur];
    // frag loads first (ds_read), then prefetch issue, then MFMA/VALU
    bf16x8 kf[2][4], vf[2][4];
#pragma unroll
    for (int t32 = 0; t32 < 2; ++t32)
#pragma unroll
      for (int dc = 0; dc < 4; ++dc)
        kf[t32][dc] = *(const bf16x8*)(Kc + (t32 * 32 + l32) * 64 + ((((dc << 1) | hi) ^ (l32 & 7)) << 3));
#pragma unroll
    for (int dt = 0; dt < 2; ++dt)
#pragma unroll
      for (int cc = 0; cc < 4; ++cc)
        vf[dt][cc] = *(const bf16x8*)(Vc + (dt * 32 + l32) * 64 + ((((cc << 1) | hi) ^ (l32 & 7)) << 3));

    if (kt < 15) {     // async prefetch next tile into buf[1-cur]
      const int kn = kt + 1, nb = 1 - cur;
#pragma unroll
      for (int j = 0; j < 2; ++j) {
        int e = tid + 256 * j, r = e >> 3, c8 = e & 7;
        CP16(Kp + (size_t)(kn * 64 + r) * 64 + ((c8 ^ (r & 7)) << 3), &Ks[nb][e * 8]);
        CP16(Vp + (size_t)r * SEQ + kn * 64 + ((c8 ^ (r & 7)) << 3), &Vts[nb][e * 8]);
      }
    }

    // S^T: st[t32] holds S^T[key = t32*32 + (r&3)+8*(r>>2)+4*hi][q = l32]
    f32x16 st[2];
#pragma unroll
    for (int t32 = 0; t32 < 2; ++t32) {
      f32x16 s = {};
#pragma unroll
      for (int dc = 0; dc < 4; ++dc)
        s = __builtin_amdgcn_mfma_f32_32x32x16_bf16(kf[t32][dc], qf[dc], s, 0, 0, 0);
      st[t32] = s;
    }

    // online softmax: lane holds 32 scores; partner (^32) has the other 32
    float tmax = st[0][0];
#pragma unroll
    for (int t32 = 0; t32 < 2; ++t32)
#pragma unroll
      for (int e = 0; e < 16; ++e) tmax = fmaxf(tmax, st[t32][e]);
    tmax = fmaxf(tmax, __shfl_xor(tmax, 32));
    const float mnew = fmaxf(m_i, tmax);
    const float alpha = __builtin_amdgcn_exp2f(m_i - mnew);
    float ssum = 0.f;
    unsigned int pf[2][8];
#pragma unroll
    for (int t32 = 0; t32 < 2; ++t32) {
      float pv[16];
#pragma unroll
      for (int e = 0; e < 16; ++e) { pv[e] = __builtin_amdgcn_exp2f(st[t32][e] - mnew); ssum += pv[e]; }
#pragma unroll
      for (int e2 = 0; e2 < 8; ++e2)
        pf[t32][e2] = packbf2_trunc(pv[2 * e2], pv[2 * e2 + 1]);
    }
    ssum += __shfl_xor(ssum, 32);
    l_i = l_i * alpha + ssum;
    m_i = mnew;
    o[0] *= alpha;
    o[1] *= alpha;

    // O^T += Vt . P^T
#pragma unroll
    for (int t32 = 0; t32 < 2; ++t32) {
#pragma unroll
      for (int hh = 0; hh < 2; ++hh) {
        bf16x8 pfrag = __builtin_bit_cast(bf16x8,
            make_uint4(pf[t32][hh * 4], pf[t32][hh * 4 + 1], pf[t32][hh * 4 + 2], pf[t32][hh * 4 + 3]));
        const int cc = 2 * t32 + hh;
#pragma unroll
        for (int dt = 0; dt < 2; ++dt)
          o[dt] = __builtin_amdgcn_mfma_f32_32x32x16_bf16(vf[dt][cc], pfrag, o[dt], 0, 0, 0);
      }
    }
  }

  // epilogue: write UNNORMALIZED O partial (bf16 RNE) + (m,l); combine normalizes.
  // lane's q = q0 + l32; o element d = dt*32 + 8*(r>>2) + 4*hi + (r&3)
  unsigned short* base = (half ? O1 : O0) + ((size_t)bb * SEQ + q0 + l32) * 768 + h * 64;
#pragma unroll
  for (int dt = 0; dt < 2; ++dt) {
#pragma unroll
    for (int run = 0; run < 4; ++run) {
      ushort4 pk;
      pk.x = f2bf(o[dt][run * 4 + 0]);
      pk.y = f2bf(o[dt][run * 4 + 1]);
      pk.z = f2bf(o[dt][run * 4 + 2]);
      pk.w = f2bf(o[dt][run * 4 + 3]);
      *(ushort4*)(base + dt * 32 + run * 8 + hi * 4) = pk;
    }
  }
  if (hi == 0)
    ml[(size_t)half * (NBH * SEQ) + bh * SEQ + q0 + l32] = make_float2(m_i, l_i);
}

// ---------------------------------------------------------------- combine partial halves
// O = (a0*O0 + a1*O1) / (a0*l0 + a1*l1), a_i = exp2(m_i - max(m0,m1)). In-place into O0.
// (proven correct in rounds 4/10/14, absmax 1.953e-3)
__global__ __launch_bounds__(256) void combine_kernel(unsigned short* __restrict__ O0,
                                                      const unsigned short* __restrict__ O1,
                                                      const float2* __restrict__ ml) {
  const int gid = blockIdx.x * 256 + threadIdx.x;   // [0, 196608)
  const int t = gid / 48, ci = gid - t * 48;        // token, 16-ch chunk
  const int ch0 = ci * 16, h = ch0 >> 6;
  const int mlrow = ((t >> 11) * NHEAD + h) * SEQ + (t & 2047);
  const float2 ml0 = ml[mlrow], ml1 = ml[NBH * SEQ + mlrow];
  const float m = fmaxf(ml0.x, ml1.x);
  const float a0 = __builtin_amdgcn_exp2f(ml0.x - m);
  const float a1 = __builtin_amdgcn_exp2f(ml1.x - m);
  const float rl = __builtin_amdgcn_rcpf(a0 * ml0.y + a1 * ml1.y);
  const float s0 = a0 * rl, s1 = a1 * rl;
  unsigned short* p0 = O0 + (size_t)t * 768 + ch0;
  const unsigned short* p1 = O1 + (size_t)t * 768 + ch0;
  uint4 x[2], y[2];
  x[0] = *(const uint4*)p0;       x[1] = *(const uint4*)(p0 + 8);
  y[0] = *(const uint4*)p1;       y[1] = *(const uint4*)(p1 + 8);
#pragma unroll
  for (int q = 0; q < 2; ++q) {
    unsigned int* xu = (unsigned int*)&x[q];
    const unsigned int* yu = (const unsigned int*)&y[q];
#pragma unroll
    for (int e = 0; e < 4; ++e) {
      const unsigned int u0 = xu[e], u1 = yu[e];
      const float lo = bfu2f(u0 << 16) * s0 + bfu2f(u1 << 16) * s1;
      const float hi = bfu2f(u0 & 0xFFFF0000u) * s0 + bfu2f(u1 & 0xFFFF0000u) * s1;
      xu[e] = ((unsigned int)f2bf(hi) << 16) | f2bf(lo);
    }
  }
  *(uint4*)p0 = x[0];
  *(uint4*)(p0 + 8) = x[1];
}

// ---------------------------------------------------------------- launch
extern "C" void kernel_launch(void* const* d_in, const int* in_sizes, int n_in,
                              void* d_out, int out_size, void* d_ws, size_t ws_size,
                              hipStream_t stream) {
  const float* x      = (const float*)d_in[0];
  const float* qkv_w  = (const float*)d_in[1];
  const float* qkv_b  = (const float*)d_in[2];
  const float* proj_w = (const float*)d_in[3];
  const float* proj_b = (const float*)d_in[4];
  float* out = (float*)d_out;

  unsigned short* xb  = (unsigned short*)d_ws;     // dead after gemm1 -> O1 partial
  unsigned short* wqb = xb + 3145728;              // dead after gemm1 -> ml partials
  unsigned short* wpb = wqb + 1769472;
  unsigned short* Qb  = wpb + 589824;
  unsigned short* Kb  = Qb + 3145728;
  unsigned short* Vtb = Kb + 3145728;
  unsigned short* Ab  = Vtb + 3145728;             // O0 partial, combined in-place

  cvt3_kernel<<<5376, 256, 0, stream>>>((const float4*)x, (const float4*)qkv_w, (const float4*)proj_w,
                                        (ushort4*)xb, (ushort4*)wqb, (ushort4*)wpb);
  // gemm1: 64x192 @ 512 threads (8 waves/tile), grid (12,64) = 768 blocks = exactly 3/CU
  gemm_kernel<64, 192, 512, 0><<<dim3(12, 64), 512, 0, stream>>>(xb, wqb, qkv_b, Qb, Kb, Vtb, nullptr);
  // attn: 4-wave blocks, 2-way key split (R14, measured 50.7-51.4 µs)
  attn_kernel<<<768, 256, 0, stream>>>(Qb, Kb, Vtb, Ab, xb, (float2*)wqb);
  combine_kernel<<<768, 256, 0, stream>>>(Ab, xb, (const float2*)wqb);
  gemm_kernel<64, 96, 256, 1><<<dim3(8, 64), 256, 0, stream>>>(Ab, wpb, proj_b, nullptr, nullptr, nullptr, out);
}

// Round 17
// 161.540 us; speedup vs baseline: 1.0283x; 1.0158x over previous
//
#include <hip/hip_runtime.h>
#include <hip/hip_bf16.h>

typedef __bf16 bf16x8 __attribute__((ext_vector_type(8)));
typedef float f32x4 __attribute__((ext_vector_type(4)));
typedef float f32x16 __attribute__((ext_vector_type(16)));

#define SEQ   2048
#define NHEAD 12
#define NBH   24
#define QSCALE 0.18033688011112042f   // head_dim^-0.5 * log2(e)

// async global->LDS 16B copy; lds dest must be wave-uniform base + lane*16
#define CP16(g, l) __builtin_amdgcn_global_load_lds( \
    (const __attribute__((address_space(1))) unsigned int*)(g), \
    (__attribute__((address_space(3))) unsigned int*)(l), 16, 0, 0)

__device__ __forceinline__ unsigned short f2bf(float f) {
  unsigned int u = __builtin_bit_cast(unsigned int, f);
  u += 0x7FFFu + ((u >> 16) & 1u);
  return (unsigned short)(u >> 16);
}
__device__ __forceinline__ float bfu2f(unsigned int lo16_as_hi) {
  return __builtin_bit_cast(float, lo16_as_hi);
}
// truncating pack of two f32 -> bf16x2 in one v_perm_b32 (P in [0,1]; dominant weight is
// exactly 1.0 under running-max so top terms carry zero pack error — PROVEN at 1.95e-3)
__device__ __forceinline__ unsigned int packbf2_trunc(float lo, float hi) {
  return __builtin_amdgcn_perm(__builtin_bit_cast(unsigned int, hi),
                               __builtin_bit_cast(unsigned int, lo), 0x07060302u);
}

// ---------------------------------------------------------------- fused cvt fp32->bf16
#define NX4  786432
#define NW14 442368
__global__ __launch_bounds__(256) void cvt3_kernel(const float4* __restrict__ x,
                                                   const float4* __restrict__ w1,
                                                   const float4* __restrict__ w2,
                                                   ushort4* __restrict__ xo,
                                                   ushort4* __restrict__ w1o,
                                                   ushort4* __restrict__ w2o) {
  int i = blockIdx.x * 256 + threadIdx.x;
  const float4* s;
  ushort4* d;
  int j = i;
  if (i < NX4)               { s = x;  d = xo; }
  else if (i < NX4 + NW14)   { s = w1; d = w1o; j = i - NX4; }
  else                       { s = w2; d = w2o; j = i - (NX4 + NW14); }
  float4 v = s[j];
  ushort4 r;
  r.x = f2bf(v.x); r.y = f2bf(v.y); r.z = f2bf(v.z); r.w = f2bf(v.w);
  d[j] = r;
}

// ---------------------------------------------------------------- GEMM  C = X @ W^T (+bias)
// Round-17: gemm1 reverted to R13/R14 measured-best (64x96 @ 256t, 1536 blocks = 6/CU).
// gemm2 gets the ONE proven GEMM lever (co-residency, R13 +3 µs): 64x64 @ 256t, grid
// (12,64) = 768 blocks = exactly 3/CU, LDS 16 KB, acc 16 VGPR. GEMM record: tile shape
// (R7), dbuf/sync-count (R9), XCD swizzle (R7), big-tile (R12), 8-wave sharing (R15/R16)
// all null — only co-resident-block TLP moved the needle.
template <int BM, int BN, int NTH, int MODE>
__global__ __launch_bounds__(NTH) void gemm_kernel(const unsigned short* __restrict__ X,
                                                   const unsigned short* __restrict__ W,
                                                   const float* __restrict__ bias,
                                                   unsigned short* __restrict__ Qb,
                                                   unsigned short* __restrict__ Kb,
                                                   unsigned short* __restrict__ Vtb,
                                                   float* __restrict__ Out) {
  constexpr int K = 768, BK = 64;
  constexpr int WAVES_N = (NTH / 64) / 2;
  constexpr int WM = BM / 2, WN = BN / WAVES_N;
  constexpr int MT = WM / 16, NT = WN / 16;
  __shared__ __align__(16) unsigned short Xs[BM * BK];
  __shared__ __align__(16) unsigned short Ws[BN * BK];

  const int tid = threadIdx.x;
  const int w = tid >> 6, lane = tid & 63, quad = lane >> 4, m16 = lane & 15;
  const int wm = w & 1, wn = w >> 1;
  const int row0 = blockIdx.y * BM, col0 = blockIdx.x * BN;

  f32x4 acc[MT][NT];
#pragma unroll
  for (int mt = 0; mt < MT; ++mt)
#pragma unroll
    for (int nt = 0; nt < NT; ++nt) acc[mt][nt] = (f32x4){0.f, 0.f, 0.f, 0.f};

  for (int k0 = 0; k0 < K; k0 += BK) {
    __syncthreads();
#pragma unroll
    for (int j = 0; j < BM * 8 / NTH; ++j) {
      int e = tid + NTH * j, r = e >> 3, c8 = e & 7;
      CP16(X + (size_t)(row0 + r) * 768 + k0 + ((c8 ^ (r & 7)) << 3), Xs + e * 8);
    }
#pragma unroll
    for (int j = 0; j < BN * 8 / NTH; ++j) {
      int e = tid + NTH * j, r = e >> 3, c8 = e & 7;
      CP16(W + (size_t)(col0 + r) * 768 + k0 + ((c8 ^ (r & 7)) << 3), Ws + e * 8);
    }
    __syncthreads();
#pragma unroll
    for (int ks = 0; ks < 2; ++ks) {
      const int sw = ((quad + 4 * ks) ^ (m16 & 7)) << 3;
      bf16x8 a[MT], b[NT];
#pragma unroll
      for (int mt = 0; mt < MT; ++mt)
        a[mt] = *(const bf16x8*)(Xs + (wm * WM + mt * 16 + m16) * BK + sw);
#pragma unroll
      for (int nt = 0; nt < NT; ++nt)
        b[nt] = *(const bf16x8*)(Ws + (wn * WN + nt * 16 + m16) * BK + sw);
#pragma unroll
      for (int mt = 0; mt < MT; ++mt)
#pragma unroll
        for (int nt = 0; nt < NT; ++nt)
          acc[mt][nt] = __builtin_amdgcn_mfma_f32_16x16x32_bf16(a[mt], b[nt], acc[mt][nt], 0, 0, 0);
    }
  }

#pragma unroll
  for (int mt = 0; mt < MT; ++mt) {
#pragma unroll
    for (int nt = 0; nt < NT; ++nt) {
      const int m0 = row0 + wm * WM + mt * 16 + quad * 4;
      const int c = col0 + wn * WN + nt * 16 + m16;
      const float bia = bias[c];
      f32x4 v = acc[mt][nt];
      if constexpr (MODE == 0) {
        const int bidx = m0 >> 11, ns = m0 & 2047;
        if (c < 1536) {   // Q or K: [bh][n][d]
          unsigned short* dst;
          float sc;
          int cc;
          if (c < 768) { cc = c; dst = Qb; sc = QSCALE; }
          else         { cc = c - 768; dst = Kb; sc = 1.0f; }
          const int h = cc >> 6, d = cc & 63;
          unsigned short* p = dst + ((size_t)(bidx * NHEAD + h) * SEQ + ns) * 64 + d;
          p[0]   = f2bf((v[0] + bia) * sc);
          p[64]  = f2bf((v[1] + bia) * sc);
          p[128] = f2bf((v[2] + bia) * sc);
          p[192] = f2bf((v[3] + bia) * sc);
        } else {          // V transposed [bh][d][n], sigma-permuted keys (bits2<->3 of n&15)
          const int cc = c - 1536, h = cc >> 6, d = cc & 63;
          const int ns2 = (ns & ~12) | ((ns & 4) << 1) | ((ns & 8) >> 1);
          ushort4 pk;
          pk.x = f2bf(v[0] + bia); pk.y = f2bf(v[1] + bia);
          pk.z = f2bf(v[2] + bia); pk.w = f2bf(v[3] + bia);
          *(ushort4*)(Vtb + ((size_t)(bidx * NHEAD + h) * 64 + d) * SEQ + ns2) = pk;
        }
      } else {
        float* o = Out + (size_t)m0 * 768 + c;
        o[0]       = v[0] + bia;
        o[768]     = v[1] + bia;
        o[2 * 768] = v[2] + bia;
        o[3 * 768] = v[3] + bia;
      }
    }
  }
}

// ---------------------------------------------------------------- flash attention
// R14 kernel (measured 50.7-51.4 µs across 3 rounds — the 4-wave-block win). 768 blocks =
// 24 bh x 16 q-tiles(128) x 2 key-halves; 256 threads = 4 waves x 32 q. Each staged 16 KB
// K/V tile + barrier serves 2x the q-rows of the R0 structure. Per-wave inner loop = R0
// verbatim. Key-split epilogue + combine proven (absmax 1.953e-3).
__global__ __launch_bounds__(256) void attn_kernel(const unsigned short* __restrict__ Qb,
                                                   const unsigned short* __restrict__ Kb,
                                                   const unsigned short* __restrict__ Vtb,
                                                   unsigned short* __restrict__ O0,
                                                   unsigned short* __restrict__ O1,
                                                   float2* __restrict__ ml) {
  __shared__ __align__(16) unsigned short Ks[2][64 * 64];
  __shared__ __align__(16) unsigned short Vts[2][64 * 64];

  const int tid = threadIdx.x;
  const int w = tid >> 6, lane = tid & 63, hi = lane >> 5, l32 = lane & 31;
  const int bh = blockIdx.x % NBH;          // same bh -> same XCD (24%8==0, 768%24==0)
  const int rest = blockIdx.x / NBH;        // [0,32)
  const int qt = rest & 15, half = rest >> 4;
  const int bb = bh / NHEAD, h = bh % NHEAD;
  const int q0 = qt * 128 + w * 32;         // wave w owns q rows [q0, q0+32)

  const unsigned short* Qp = Qb + (size_t)bh * SEQ * 64;
  const unsigned short* Kp = Kb + (size_t)bh * SEQ * 64 + (size_t)half * 16 * 4096;
  const unsigned short* Vp = Vtb + (size_t)bh * 64 * SEQ + half * 1024;

  // Q B-frags: lane holds Q[q0+l32][dc*16 + hi*8 + j]
  bf16x8 qf[4];
#pragma unroll
  for (int dc = 0; dc < 4; ++dc)
    qf[dc] = *(const bf16x8*)(Qp + (size_t)(q0 + l32) * 64 + dc * 16 + hi * 8);

  // prologue: stage tile 0 (of this half) into buf 0 — 256 threads, j<2 covers 512 chunks
#pragma unroll
  for (int j = 0; j < 2; ++j) {
    int e = tid + 256 * j, r = e >> 3, c8 = e & 7;
    CP16(Kp + (size_t)r * 64 + ((c8 ^ (r & 7)) << 3), &Ks[0][e * 8]);
    CP16(Vp + (size_t)r * SEQ + ((c8 ^ (r & 7)) << 3), &Vts[0][e * 8]);
  }

  f32x16 o[2] = {};
  float m_i = -3.0e38f, l_i = 0.f;

  for (int kt = 0; kt < 16; ++kt) {
    const int cur = kt & 1;
    __syncthreads();   // drains vmcnt -> buf[cur] ready; all waves done reading buf[1-cur]

    const unsigned short* Kc = Ks[cur];
    const unsigned short* Vc = Vts[cur];
    // frag loads first (ds_read), then prefetch issue, then MFMA/VALU
    bf16x8 kf[2][4], vf[2][4];
#pragma unroll
    for (int t32 = 0; t32 < 2; ++t32)
#pragma unroll
      for (int dc = 0; dc < 4; ++dc)
        kf[t32][dc] = *(const bf16x8*)(Kc + (t32 * 32 + l32) * 64 + ((((dc << 1) | hi) ^ (l32 & 7)) << 3));
#pragma unroll
    for (int dt = 0; dt < 2; ++dt)
#pragma unroll
      for (int cc = 0; cc < 4; ++cc)
        vf[dt][cc] = *(const bf16x8*)(Vc + (dt * 32 + l32) * 64 + ((((cc << 1) | hi) ^ (l32 & 7)) << 3));

    if (kt < 15) {     // async prefetch next tile into buf[1-cur]
      const int kn = kt + 1, nb = 1 - cur;
#pragma unroll
      for (int j = 0; j < 2; ++j) {
        int e = tid + 256 * j, r = e >> 3, c8 = e & 7;
        CP16(Kp + (size_t)(kn * 64 + r) * 64 + ((c8 ^ (r & 7)) << 3), &Ks[nb][e * 8]);
        CP16(Vp + (size_t)r * SEQ + kn * 64 + ((c8 ^ (r & 7)) << 3), &Vts[nb][e * 8]);
      }
    }

    // S^T: st[t32] holds S^T[key = t32*32 + (r&3)+8*(r>>2)+4*hi][q = l32]
    f32x16 st[2];
#pragma unroll
    for (int t32 = 0; t32 < 2; ++t32) {
      f32x16 s = {};
#pragma unroll
      for (int dc = 0; dc < 4; ++dc)
        s = __builtin_amdgcn_mfma_f32_32x32x16_bf16(kf[t32][dc], qf[dc], s, 0, 0, 0);
      st[t32] = s;
    }

    // online softmax: lane holds 32 scores; partner (^32) has the other 32
    float tmax = st[0][0];
#pragma unroll
    for (int t32 = 0; t32 < 2; ++t32)
#pragma unroll
      for (int e = 0; e < 16; ++e) tmax = fmaxf(tmax, st[t32][e]);
    tmax = fmaxf(tmax, __shfl_xor(tmax, 32));
    const float mnew = fmaxf(m_i, tmax);
    const float alpha = __builtin_amdgcn_exp2f(m_i - mnew);
    float ssum = 0.f;
    unsigned int pf[2][8];
#pragma unroll
    for (int t32 = 0; t32 < 2; ++t32) {
      float pv[16];
#pragma unroll
      for (int e = 0; e < 16; ++e) { pv[e] = __builtin_amdgcn_exp2f(st[t32][e] - mnew); ssum += pv[e]; }
#pragma unroll
      for (int e2 = 0; e2 < 8; ++e2)
        pf[t32][e2] = packbf2_trunc(pv[2 * e2], pv[2 * e2 + 1]);
    }
    ssum += __shfl_xor(ssum, 32);
    l_i = l_i * alpha + ssum;
    m_i = mnew;
    o[0] *= alpha;
    o[1] *= alpha;

    // O^T += Vt . P^T
#pragma unroll
    for (int t32 = 0; t32 < 2; ++t32) {
#pragma unroll
      for (int hh = 0; hh < 2; ++hh) {
        bf16x8 pfrag = __builtin_bit_cast(bf16x8,
            make_uint4(pf[t32][hh * 4], pf[t32][hh * 4 + 1], pf[t32][hh * 4 + 2], pf[t32][hh * 4 + 3]));
        const int cc = 2 * t32 + hh;
#pragma unroll
        for (int dt = 0; dt < 2; ++dt)
          o[dt] = __builtin_amdgcn_mfma_f32_32x32x16_bf16(vf[dt][cc], pfrag, o[dt], 0, 0, 0);
      }
    }
  }

  // epilogue: write UNNORMALIZED O partial (bf16 RNE) + (m,l); combine normalizes.
  // lane's q = q0 + l32; o element d = dt*32 + 8*(r>>2) + 4*hi + (r&3)
  unsigned short* base = (half ? O1 : O0) + ((size_t)bb * SEQ + q0 + l32) * 768 + h * 64;
#pragma unroll
  for (int dt = 0; dt < 2; ++dt) {
#pragma unroll
    for (int run = 0; run < 4; ++run) {
      ushort4 pk;
      pk.x = f2bf(o[dt][run * 4 + 0]);
      pk.y = f2bf(o[dt][run * 4 + 1]);
      pk.z = f2bf(o[dt][run * 4 + 2]);
      pk.w = f2bf(o[dt][run * 4 + 3]);
      *(ushort4*)(base + dt * 32 + run * 8 + hi * 4) = pk;
    }
  }
  if (hi == 0)
    ml[(size_t)half * (NBH * SEQ) + bh * SEQ + q0 + l32] = make_float2(m_i, l_i);
}

// ---------------------------------------------------------------- combine partial halves
// O = (a0*O0 + a1*O1) / (a0*l0 + a1*l1), a_i = exp2(m_i - max(m0,m1)). In-place into O0.
// (proven correct in rounds 4/10/14, absmax 1.953e-3)
__global__ __launch_bounds__(256) void combine_kernel(unsigned short* __restrict__ O0,
                                                      const unsigned short* __restrict__ O1,
                                                      const float2* __restrict__ ml) {
  const int gid = blockIdx.x * 256 + threadIdx.x;   // [0, 196608)
  const int t = gid / 48, ci = gid - t * 48;        // token, 16-ch chunk
  const int ch0 = ci * 16, h = ch0 >> 6;
  const int mlrow = ((t >> 11) * NHEAD + h) * SEQ + (t & 2047);
  const float2 ml0 = ml[mlrow], ml1 = ml[NBH * SEQ + mlrow];
  const float m = fmaxf(ml0.x, ml1.x);
  const float a0 = __builtin_amdgcn_exp2f(ml0.x - m);
  const float a1 = __builtin_amdgcn_exp2f(ml1.x - m);
  const float rl = __builtin_amdgcn_rcpf(a0 * ml0.y + a1 * ml1.y);
  const float s0 = a0 * rl, s1 = a1 * rl;
  unsigned short* p0 = O0 + (size_t)t * 768 + ch0;
  const unsigned short* p1 = O1 + (size_t)t * 768 + ch0;
  uint4 x[2], y[2];
  x[0] = *(const uint4*)p0;       x[1] = *(const uint4*)(p0 + 8);
  y[0] = *(const uint4*)p1;       y[1] = *(const uint4*)(p1 + 8);
#pragma unroll
  for (int q = 0; q < 2; ++q) {
    unsigned int* xu = (unsigned int*)&x[q];
    const unsigned int* yu = (const unsigned int*)&y[q];
#pragma unroll
    for (int e = 0; e < 4; ++e) {
      const unsigned int u0 = xu[e], u1 = yu[e];
      const float lo = bfu2f(u0 << 16) * s0 + bfu2f(u1 << 16) * s1;
      const float hi = bfu2f(u0 & 0xFFFF0000u) * s0 + bfu2f(u1 & 0xFFFF0000u) * s1;
      xu[e] = ((unsigned int)f2bf(hi) << 16) | f2bf(lo);
    }
  }
  *(uint4*)p0 = x[0];
  *(uint4*)(p0 + 8) = x[1];
}

// ---------------------------------------------------------------- launch
extern "C" void kernel_launch(void* const* d_in, const int* in_sizes, int n_in,
                              void* d_out, int out_size, void* d_ws, size_t ws_size,
                              hipStream_t stream) {
  const float* x      = (const float*)d_in[0];
  const float* qkv_w  = (const float*)d_in[1];
  const float* qkv_b  = (const float*)d_in[2];
  const float* proj_w = (const float*)d_in[3];
  const float* proj_b = (const float*)d_in[4];
  float* out = (float*)d_out;

  unsigned short* xb  = (unsigned short*)d_ws;     // dead after gemm1 -> O1 partial
  unsigned short* wqb = xb + 3145728;              // dead after gemm1 -> ml partials
  unsigned short* wpb = wqb + 1769472;
  unsigned short* Qb  = wpb + 589824;
  unsigned short* Kb  = Qb + 3145728;
  unsigned short* Vtb = Kb + 3145728;
  unsigned short* Ab  = Vtb + 3145728;             // O0 partial, combined in-place

  cvt3_kernel<<<5376, 256, 0, stream>>>((const float4*)x, (const float4*)qkv_w, (const float4*)proj_w,
                                        (ushort4*)xb, (ushort4*)wqb, (ushort4*)wpb);
  // gemm1: 64x96 @ 256t -> 1536 blocks = 6/CU (R13/R14 measured best)
  gemm_kernel<64, 96, 256, 0><<<dim3(24, 64), 256, 0, stream>>>(xb, wqb, qkv_b, Qb, Kb, Vtb, nullptr);
  // attn: 4-wave blocks, 2-way key split (R14, measured 50.7-51.4 µs)
  attn_kernel<<<768, 256, 0, stream>>>(Qb, Kb, Vtb, Ab, xb, (float2*)wqb);
  combine_kernel<<<768, 256, 0, stream>>>(Ab, xb, (const float2*)wqb);
  // gemm2: 64x64 @ 256t -> grid (12,64) = 768 blocks = exactly 3/CU (co-residency lever)
  gemm_kernel<64, 64, 256, 1><<<dim3(12, 64), 256, 0, stream>>>(Ab, wpb, proj_b, nullptr, nullptr, nullptr, out);
}

// Round 18
// 161.191 us; speedup vs baseline: 1.0306x; 1.0022x over previous
//
#include <hip/hip_runtime.h>
#include <hip/hip_bf16.h>

typedef __bf16 bf16x8 __attribute__((ext_vector_type(8)));
typedef float f32x4 __attribute__((ext_vector_type(4)));
typedef float f32x16 __attribute__((ext_vector_type(16)));

#define SEQ   2048
#define NHEAD 12
#define NBH   24
#define QSCALE 0.18033688011112042f   // head_dim^-0.5 * log2(e)

// async global->LDS 16B copy; lds dest must be wave-uniform base + lane*16
#define CP16(g, l) __builtin_amdgcn_global_load_lds( \
    (const __attribute__((address_space(1))) unsigned int*)(g), \
    (__attribute__((address_space(3))) unsigned int*)(l), 16, 0, 0)

__device__ __forceinline__ unsigned short f2bf(float f) {
  unsigned int u = __builtin_bit_cast(unsigned int, f);
  u += 0x7FFFu + ((u >> 16) & 1u);
  return (unsigned short)(u >> 16);
}
__device__ __forceinline__ float bfu2f(unsigned int lo16_as_hi) {
  return __builtin_bit_cast(float, lo16_as_hi);
}
// truncating pack of two f32 -> bf16x2 in one v_perm_b32 (P in [0,1]; dominant weight is
// exactly 1.0 under running-max so top terms carry zero pack error — PROVEN at 1.95e-3)
__device__ __forceinline__ unsigned int packbf2_trunc(float lo, float hi) {
  return __builtin_amdgcn_perm(__builtin_bit_cast(unsigned int, hi),
                               __builtin_bit_cast(unsigned int, lo), 0x07060302u);
}

// ---------------------------------------------------------------- fused cvt fp32->bf16
#define NX4  786432
#define NW14 442368
__global__ __launch_bounds__(256) void cvt3_kernel(const float4* __restrict__ x,
                                                   const float4* __restrict__ w1,
                                                   const float4* __restrict__ w2,
                                                   ushort4* __restrict__ xo,
                                                   ushort4* __restrict__ w1o,
                                                   ushort4* __restrict__ w2o) {
  int i = blockIdx.x * 256 + threadIdx.x;
  const float4* s;
  ushort4* d;
  int j = i;
  if (i < NX4)               { s = x;  d = xo; }
  else if (i < NX4 + NW14)   { s = w1; d = w1o; j = i - NX4; }
  else                       { s = w2; d = w2o; j = i - (NX4 + NW14); }
  float4 v = s[j];
  ushort4 r;
  r.x = f2bf(v.x); r.y = f2bf(v.y); r.z = f2bf(v.z); r.w = f2bf(v.w);
  d[j] = r;
}

// ---------------------------------------------------------------- GEMM  C = X @ W^T (+bias)
// Round-18: gemm1 co-residency notched up (the ONE proven GEMM lever, +3 µs in R13, +1 in
// R17): 64x96 -> 64x64 @ 256t. VGPR drops ~80 -> ~64, lifting the residency cap from 6 to
// 8 blocks/CU (LDS 16 KB allows 10); grid (36,64) = 2304 blocks = 9/CU (8 resident + one
// final round). +20% staged bytes through +33% parallel channels — the R13-winning
// tradeoff. gemm2 stays R17 (64x64 @ 768 blocks = 3/CU).
template <int BM, int BN, int NTH, int MODE>
__global__ __launch_bounds__(NTH) void gemm_kernel(const unsigned short* __restrict__ X,
                                                   const unsigned short* __restrict__ W,
                                                   const float* __restrict__ bias,
                                                   unsigned short* __restrict__ Qb,
                                                   unsigned short* __restrict__ Kb,
                                                   unsigned short* __restrict__ Vtb,
                                                   float* __restrict__ Out) {
  constexpr int K = 768, BK = 64;
  constexpr int WAVES_N = (NTH / 64) / 2;
  constexpr int WM = BM / 2, WN = BN / WAVES_N;
  constexpr int MT = WM / 16, NT = WN / 16;
  __shared__ __align__(16) unsigned short Xs[BM * BK];
  __shared__ __align__(16) unsigned short Ws[BN * BK];

  const int tid = threadIdx.x;
  const int w = tid >> 6, lane = tid & 63, quad = lane >> 4, m16 = lane & 15;
  const int wm = w & 1, wn = w >> 1;
  const int row0 = blockIdx.y * BM, col0 = blockIdx.x * BN;

  f32x4 acc[MT][NT];
#pragma unroll
  for (int mt = 0; mt < MT; ++mt)
#pragma unroll
    for (int nt = 0; nt < NT; ++nt) acc[mt][nt] = (f32x4){0.f, 0.f, 0.f, 0.f};

  for (int k0 = 0; k0 < K; k0 += BK) {
    __syncthreads();
#pragma unroll
    for (int j = 0; j < BM * 8 / NTH; ++j) {
      int e = tid + NTH * j, r = e >> 3, c8 = e & 7;
      CP16(X + (size_t)(row0 + r) * 768 + k0 + ((c8 ^ (r & 7)) << 3), Xs + e * 8);
    }
#pragma unroll
    for (int j = 0; j < BN * 8 / NTH; ++j) {
      int e = tid + NTH * j, r = e >> 3, c8 = e & 7;
      CP16(W + (size_t)(col0 + r) * 768 + k0 + ((c8 ^ (r & 7)) << 3), Ws + e * 8);
    }
    __syncthreads();
#pragma unroll
    for (int ks = 0; ks < 2; ++ks) {
      const int sw = ((quad + 4 * ks) ^ (m16 & 7)) << 3;
      bf16x8 a[MT], b[NT];
#pragma unroll
      for (int mt = 0; mt < MT; ++mt)
        a[mt] = *(const bf16x8*)(Xs + (wm * WM + mt * 16 + m16) * BK + sw);
#pragma unroll
      for (int nt = 0; nt < NT; ++nt)
        b[nt] = *(const bf16x8*)(Ws + (wn * WN + nt * 16 + m16) * BK + sw);
#pragma unroll
      for (int mt = 0; mt < MT; ++mt)
#pragma unroll
        for (int nt = 0; nt < NT; ++nt)
          acc[mt][nt] = __builtin_amdgcn_mfma_f32_16x16x32_bf16(a[mt], b[nt], acc[mt][nt], 0, 0, 0);
    }
  }

#pragma unroll
  for (int mt = 0; mt < MT; ++mt) {
#pragma unroll
    for (int nt = 0; nt < NT; ++nt) {
      const int m0 = row0 + wm * WM + mt * 16 + quad * 4;
      const int c = col0 + wn * WN + nt * 16 + m16;
      const float bia = bias[c];
      f32x4 v = acc[mt][nt];
      if constexpr (MODE == 0) {
        const int bidx = m0 >> 11, ns = m0 & 2047;
        if (c < 1536) {   // Q or K: [bh][n][d]
          unsigned short* dst;
          float sc;
          int cc;
          if (c < 768) { cc = c; dst = Qb; sc = QSCALE; }
          else         { cc = c - 768; dst = Kb; sc = 1.0f; }
          const int h = cc >> 6, d = cc & 63;
          unsigned short* p = dst + ((size_t)(bidx * NHEAD + h) * SEQ + ns) * 64 + d;
          p[0]   = f2bf((v[0] + bia) * sc);
          p[64]  = f2bf((v[1] + bia) * sc);
          p[128] = f2bf((v[2] + bia) * sc);
          p[192] = f2bf((v[3] + bia) * sc);
        } else {          // V transposed [bh][d][n], sigma-permuted keys (bits2<->3 of n&15)
          const int cc = c - 1536, h = cc >> 6, d = cc & 63;
          const int ns2 = (ns & ~12) | ((ns & 4) << 1) | ((ns & 8) >> 1);
          ushort4 pk;
          pk.x = f2bf(v[0] + bia); pk.y = f2bf(v[1] + bia);
          pk.z = f2bf(v[2] + bia); pk.w = f2bf(v[3] + bia);
          *(ushort4*)(Vtb + ((size_t)(bidx * NHEAD + h) * 64 + d) * SEQ + ns2) = pk;
        }
      } else {
        float* o = Out + (size_t)m0 * 768 + c;
        o[0]       = v[0] + bia;
        o[768]     = v[1] + bia;
        o[2 * 768] = v[2] + bia;
        o[3 * 768] = v[3] + bia;
      }
    }
  }
}

// ---------------------------------------------------------------- flash attention
// R14 kernel (measured 50.7-52.4 µs across 4 rounds — the 4-wave-block win). 768 blocks =
// 24 bh x 16 q-tiles(128) x 2 key-halves; 256 threads = 4 waves x 32 q. Each staged 16 KB
// K/V tile + barrier serves 2x the q-rows of the R0 structure. Per-wave inner loop = R0
// verbatim. Key-split epilogue + combine proven (absmax 1.953e-3).
__global__ __launch_bounds__(256) void attn_kernel(const unsigned short* __restrict__ Qb,
                                                   const unsigned short* __restrict__ Kb,
                                                   const unsigned short* __restrict__ Vtb,
                                                   unsigned short* __restrict__ O0,
                                                   unsigned short* __restrict__ O1,
                                                   float2* __restrict__ ml) {
  __shared__ __align__(16) unsigned short Ks[2][64 * 64];
  __shared__ __align__(16) unsigned short Vts[2][64 * 64];

  const int tid = threadIdx.x;
  const int w = tid >> 6, lane = tid & 63, hi = lane >> 5, l32 = lane & 31;
  const int bh = blockIdx.x % NBH;          // same bh -> same XCD (24%8==0, 768%24==0)
  const int rest = blockIdx.x / NBH;        // [0,32)
  const int qt = rest & 15, half = rest >> 4;
  const int bb = bh / NHEAD, h = bh % NHEAD;
  const int q0 = qt * 128 + w * 32;         // wave w owns q rows [q0, q0+32)

  const unsigned short* Qp = Qb + (size_t)bh * SEQ * 64;
  const unsigned short* Kp = Kb + (size_t)bh * SEQ * 64 + (size_t)half * 16 * 4096;
  const unsigned short* Vp = Vtb + (size_t)bh * 64 * SEQ + half * 1024;

  // Q B-frags: lane holds Q[q0+l32][dc*16 + hi*8 + j]
  bf16x8 qf[4];
#pragma unroll
  for (int dc = 0; dc < 4; ++dc)
    qf[dc] = *(const bf16x8*)(Qp + (size_t)(q0 + l32) * 64 + dc * 16 + hi * 8);

  // prologue: stage tile 0 (of this half) into buf 0 — 256 threads, j<2 covers 512 chunks
#pragma unroll
  for (int j = 0; j < 2; ++j) {
    int e = tid + 256 * j, r = e >> 3, c8 = e & 7;
    CP16(Kp + (size_t)r * 64 + ((c8 ^ (r & 7)) << 3), &Ks[0][e * 8]);
    CP16(Vp + (size_t)r * SEQ + ((c8 ^ (r & 7)) << 3), &Vts[0][e * 8]);
  }

  f32x16 o[2] = {};
  float m_i = -3.0e38f, l_i = 0.f;

  for (int kt = 0; kt < 16; ++kt) {
    const int cur = kt & 1;
    __syncthreads();   // drains vmcnt -> buf[cur] ready; all waves done reading buf[1-cur]

    const unsigned short* Kc = Ks[cur];
    const unsigned short* Vc = Vts[cur];
    // frag loads first (ds_read), then prefetch issue, then MFMA/VALU
    bf16x8 kf[2][4], vf[2][4];
#pragma unroll
    for (int t32 = 0; t32 < 2; ++t32)
#pragma unroll
      for (int dc = 0; dc < 4; ++dc)
        kf[t32][dc] = *(const bf16x8*)(Kc + (t32 * 32 + l32) * 64 + ((((dc << 1) | hi) ^ (l32 & 7)) << 3));
#pragma unroll
    for (int dt = 0; dt < 2; ++dt)
#pragma unroll
      for (int cc = 0; cc < 4; ++cc)
        vf[dt][cc] = *(const bf16x8*)(Vc + (dt * 32 + l32) * 64 + ((((cc << 1) | hi) ^ (l32 & 7)) << 3));

    if (kt < 15) {     // async prefetch next tile into buf[1-cur]
      const int kn = kt + 1, nb = 1 - cur;
#pragma unroll
      for (int j = 0; j < 2; ++j) {
        int e = tid + 256 * j, r = e >> 3, c8 = e & 7;
        CP16(Kp + (size_t)(kn * 64 + r) * 64 + ((c8 ^ (r & 7)) << 3), &Ks[nb][e * 8]);
        CP16(Vp + (size_t)r * SEQ + kn * 64 + ((c8 ^ (r & 7)) << 3), &Vts[nb][e * 8]);
      }
    }

    // S^T: st[t32] holds S^T[key = t32*32 + (r&3)+8*(r>>2)+4*hi][q = l32]
    f32x16 st[2];
#pragma unroll
    for (int t32 = 0; t32 < 2; ++t32) {
      f32x16 s = {};
#pragma unroll
      for (int dc = 0; dc < 4; ++dc)
        s = __builtin_amdgcn_mfma_f32_32x32x16_bf16(kf[t32][dc], qf[dc], s, 0, 0, 0);
      st[t32] = s;
    }

    // online softmax: lane holds 32 scores; partner (^32) has the other 32
    float tmax = st[0][0];
#pragma unroll
    for (int t32 = 0; t32 < 2; ++t32)
#pragma unroll
      for (int e = 0; e < 16; ++e) tmax = fmaxf(tmax, st[t32][e]);
    tmax = fmaxf(tmax, __shfl_xor(tmax, 32));
    const float mnew = fmaxf(m_i, tmax);
    const float alpha = __builtin_amdgcn_exp2f(m_i - mnew);
    float ssum = 0.f;
    unsigned int pf[2][8];
#pragma unroll
    for (int t32 = 0; t32 < 2; ++t32) {
      float pv[16];
#pragma unroll
      for (int e = 0; e < 16; ++e) { pv[e] = __builtin_amdgcn_exp2f(st[t32][e] - mnew); ssum += pv[e]; }
#pragma unroll
      for (int e2 = 0; e2 < 8; ++e2)
        pf[t32][e2] = packbf2_trunc(pv[2 * e2], pv[2 * e2 + 1]);
    }
    ssum += __shfl_xor(ssum, 32);
    l_i = l_i * alpha + ssum;
    m_i = mnew;
    o[0] *= alpha;
    o[1] *= alpha;

    // O^T += Vt . P^T
#pragma unroll
    for (int t32 = 0; t32 < 2; ++t32) {
#pragma unroll
      for (int hh = 0; hh < 2; ++hh) {
        bf16x8 pfrag = __builtin_bit_cast(bf16x8,
            make_uint4(pf[t32][hh * 4], pf[t32][hh * 4 + 1], pf[t32][hh * 4 + 2], pf[t32][hh * 4 + 3]));
        const int cc = 2 * t32 + hh;
#pragma unroll
        for (int dt = 0; dt < 2; ++dt)
          o[dt] = __builtin_amdgcn_mfma_f32_32x32x16_bf16(vf[dt][cc], pfrag, o[dt], 0, 0, 0);
      }
    }
  }

  // epilogue: write UNNORMALIZED O partial (bf16 RNE) + (m,l); combine normalizes.
  // lane's q = q0 + l32; o element d = dt*32 + 8*(r>>2) + 4*hi + (r&3)
  unsigned short* base = (half ? O1 : O0) + ((size_t)bb * SEQ + q0 + l32) * 768 + h * 64;
#pragma unroll
  for (int dt = 0; dt < 2; ++dt) {
#pragma unroll
    for (int run = 0; run < 4; ++run) {
      ushort4 pk;
      pk.x = f2bf(o[dt][run * 4 + 0]);
      pk.y = f2bf(o[dt][run * 4 + 1]);
      pk.z = f2bf(o[dt][run * 4 + 2]);
      pk.w = f2bf(o[dt][run * 4 + 3]);
      *(ushort4*)(base + dt * 32 + run * 8 + hi * 4) = pk;
    }
  }
  if (hi == 0)
    ml[(size_t)half * (NBH * SEQ) + bh * SEQ + q0 + l32] = make_float2(m_i, l_i);
}

// ---------------------------------------------------------------- combine partial halves
// O = (a0*O0 + a1*O1) / (a0*l0 + a1*l1), a_i = exp2(m_i - max(m0,m1)). In-place into O0.
// (proven correct in rounds 4/10/14, absmax 1.953e-3)
__global__ __launch_bounds__(256) void combine_kernel(unsigned short* __restrict__ O0,
                                                      const unsigned short* __restrict__ O1,
                                                      const float2* __restrict__ ml) {
  const int gid = blockIdx.x * 256 + threadIdx.x;   // [0, 196608)
  const int t = gid / 48, ci = gid - t * 48;        // token, 16-ch chunk
  const int ch0 = ci * 16, h = ch0 >> 6;
  const int mlrow = ((t >> 11) * NHEAD + h) * SEQ + (t & 2047);
  const float2 ml0 = ml[mlrow], ml1 = ml[NBH * SEQ + mlrow];
  const float m = fmaxf(ml0.x, ml1.x);
  const float a0 = __builtin_amdgcn_exp2f(ml0.x - m);
  const float a1 = __builtin_amdgcn_exp2f(ml1.x - m);
  const float rl = __builtin_amdgcn_rcpf(a0 * ml0.y + a1 * ml1.y);
  const float s0 = a0 * rl, s1 = a1 * rl;
  unsigned short* p0 = O0 + (size_t)t * 768 + ch0;
  const unsigned short* p1 = O1 + (size_t)t * 768 + ch0;
  uint4 x[2], y[2];
  x[0] = *(const uint4*)p0;       x[1] = *(const uint4*)(p0 + 8);
  y[0] = *(const uint4*)p1;       y[1] = *(const uint4*)(p1 + 8);
#pragma unroll
  for (int q = 0; q < 2; ++q) {
    unsigned int* xu = (unsigned int*)&x[q];
    const unsigned int* yu = (const unsigned int*)&y[q];
#pragma unroll
    for (int e = 0; e < 4; ++e) {
      const unsigned int u0 = xu[e], u1 = yu[e];
      const float lo = bfu2f(u0 << 16) * s0 + bfu2f(u1 << 16) * s1;
      const float hi = bfu2f(u0 & 0xFFFF0000u) * s0 + bfu2f(u1 & 0xFFFF0000u) * s1;
      xu[e] = ((unsigned int)f2bf(hi) << 16) | f2bf(lo);
    }
  }
  *(uint4*)p0 = x[0];
  *(uint4*)(p0 + 8) = x[1];
}

// ---------------------------------------------------------------- launch
extern "C" void kernel_launch(void* const* d_in, const int* in_sizes, int n_in,
                              void* d_out, int out_size, void* d_ws, size_t ws_size,
                              hipStream_t stream) {
  const float* x      = (const float*)d_in[0];
  const float* qkv_w  = (const float*)d_in[1];
  const float* qkv_b  = (const float*)d_in[2];
  const float* proj_w = (const float*)d_in[3];
  const float* proj_b = (const float*)d_in[4];
  float* out = (float*)d_out;

  unsigned short* xb  = (unsigned short*)d_ws;     // dead after gemm1 -> O1 partial
  unsigned short* wqb = xb + 3145728;              // dead after gemm1 -> ml partials
  unsigned short* wpb = wqb + 1769472;
  unsigned short* Qb  = wpb + 589824;
  unsigned short* Kb  = Qb + 3145728;
  unsigned short* Vtb = Kb + 3145728;
  unsigned short* Ab  = Vtb + 3145728;             // O0 partial, combined in-place

  cvt3_kernel<<<5376, 256, 0, stream>>>((const float4*)x, (const float4*)qkv_w, (const float4*)proj_w,
                                        (ushort4*)xb, (ushort4*)wqb, (ushort4*)wpb);
  // gemm1: 64x64 @ 256t -> grid (36,64) = 2304 blocks, 8 resident/CU (VGPR cap lifted)
  gemm_kernel<64, 64, 256, 0><<<dim3(36, 64), 256, 0, stream>>>(xb, wqb, qkv_b, Qb, Kb, Vtb, nullptr);
  // attn: 4-wave blocks, 2-way key split (R14, measured 50.7-52.4 µs)
  attn_kernel<<<768, 256, 0, stream>>>(Qb, Kb, Vtb, Ab, xb, (float2*)wqb);
  combine_kernel<<<768, 256, 0, stream>>>(Ab, xb, (const float2*)wqb);
  // gemm2: 64x64 @ 256t -> grid (12,64) = 768 blocks = exactly 3/CU (R17)
  gemm_kernel<64, 64, 256, 1><<<dim3(12, 64), 256, 0, stream>>>(Ab, wpb, proj_b, nullptr, nullptr, nullptr, out);
}